// Round 5
// baseline (43.846 us; speedup 1.0000x reference)
//
#include <hip/hip_runtime.h>

// Problem constants (fixed by reference: B=4, C=32, H=W=24, hid=128, out=32)
#define B_     4
#define C_     32
#define N_     576     // H*W
#define HID    128
#define OUT_   32
#define JPT    4       // j's per THREAD (register-tiled)
#define GRPS   8       // 32-lane groups per block
#define TJB    (JPT * GRPS)     // 32 j's per block
#define ISPLIT 12      // i-range split for occupancy
#define ICH    (N_ / ISPLIT)    // 48 i's per block
#define STG    (ICH * HID / (256 * 4))   // 6 float4 stages per thread

// ---------------------------------------------------------------------------
// Kernel A: per-token projections + out init (out = N*b2).
//   tokens[b,n,c] = x[(b*C+c)*N + n]
//   px[b,n,f]  = sum_c tok[c] * W1[c,f]
//   pcb[b,n,f] = sum_c tok[c] * W1[C+c,f] + b1[f]
// ---------------------------------------------------------------------------
__global__ __launch_bounds__(128) void proj_kernel(
    const float* __restrict__ x, const float* __restrict__ W1,
    const float* __restrict__ b1, const float* __restrict__ b2,
    float* __restrict__ px, float* __restrict__ pcb,
    float* __restrict__ out)
{
    const int blk = blockIdx.x;       // 0 .. B*N-1
    const int b = blk / N_;
    const int n = blk % N_;
    const int f = threadIdx.x;        // 0..127

    // out init: 2304 blocks x 32 elements = 73728 = B*OUT*N exactly.
    if (f < OUT_) {
        const int q = blk * OUT_ + f;
        out[q] = (float)N_ * b2[(q / N_) & (OUT_ - 1)];
    }

    __shared__ float tok[C_];
    if (f < C_) tok[f] = x[(b * C_ + f) * N_ + n];
    __syncthreads();

    float accx = 0.f, accc = 0.f;
#pragma unroll
    for (int c = 0; c < C_; ++c) {
        const float t = tok[c];
        accx = fmaf(t, W1[c * HID + f], accx);
        accc = fmaf(t, W1[(C_ + c) * HID + f], accc);
    }
    const int base = (b * N_ + n) * HID + f;
    px[base]  = accx;
    pcb[base] = accc + b1[f];
}

// ---------------------------------------------------------------------------
// Kernel B: pairwise relu-sum with FUSED W2 epilogue, atomic out accumulate.
//   g_part[j,f] = sum_{i in chunk(isp)} relu(px[b,i,f] + pcb[b,j,f])
//   out[b,o,j] += sum_f g_part[j,f] * W2[f,o]
// Block = 256 threads = 8 groups x 32 lanes; group owns 4 j's, lane owns a
// float4 of features. px chunk staged to LDS; g staged to same LDS region
// for the in-block 128->32 GEMM; partials atomicAdd'ed into out.
// ---------------------------------------------------------------------------
__global__ __launch_bounds__(256) void pair_fused(
    const float* __restrict__ px, const float* __restrict__ pcb,
    const float* __restrict__ W2, float* __restrict__ out)
{
    const int jt   = blockIdx.x;          // 0 .. N/TJB-1  (18)
    const int isp  = blockIdx.y;          // 0 .. ISPLIT-1 (12)
    const int b    = blockIdx.z;          // 0 .. B-1
    const int tid  = threadIdx.x;
    const int lane = tid & 31;            // f-quad index
    const int grp  = tid >> 5;            // 0..7
    const int j0   = jt * TJB + grp * JPT;

    __shared__ float smem[ICH * HID];     // 24 KB; later reused as g[32][128]

    // Burst-stage the contiguous px chunk: 6 independent 16B loads/thread.
    const float* __restrict__ src = px + ((size_t)b * N_ + isp * ICH) * HID;
    float4 tmp[STG];
#pragma unroll
    for (int k = 0; k < STG; ++k)
        tmp[k] = *(const float4*)(src + (k * 256 + tid) * 4);

    // pcb for this thread's 4 j's (overlaps with staging latency).
    float4 c[JPT];
#pragma unroll
    for (int jp = 0; jp < JPT; ++jp)
        c[jp] = *(const float4*)(pcb + ((size_t)b * N_ + j0 + jp) * HID + 4 * lane);

#pragma unroll
    for (int k = 0; k < STG; ++k)
        *(float4*)(smem + (k * 256 + tid) * 4) = tmp[k];
    __syncthreads();

    float4 acc[JPT];
#pragma unroll
    for (int jp = 0; jp < JPT; ++jp)
        acc[jp] = make_float4(0.f, 0.f, 0.f, 0.f);

#pragma unroll 4
    for (int i = 0; i < ICH; ++i) {
        const float4 a = *(const float4*)(smem + i * HID + 4 * lane);
#pragma unroll
        for (int jp = 0; jp < JPT; ++jp) {
            acc[jp].x += fmaxf(a.x + c[jp].x, 0.f);
            acc[jp].y += fmaxf(a.y + c[jp].y, 0.f);
            acc[jp].z += fmaxf(a.z + c[jp].z, 0.f);
            acc[jp].w += fmaxf(a.w + c[jp].w, 0.f);
        }
    }
    __syncthreads();   // done reading staged px

    // Stage g into LDS: group's rows (local j = grp*4+jp), lane's f-quad.
#pragma unroll
    for (int jp = 0; jp < JPT; ++jp)
        *(float4*)(smem + (grp * JPT + jp) * HID + 4 * lane) = acc[jp];
    __syncthreads();

    // Epilogue GEMM: thread -> (o = lane, group's 4 local j rows).
    // g rows broadcast via same-address b128 reads; W2 rows coalesced (L1).
    const int o = lane;
    float s0 = 0.f, s1 = 0.f, s2 = 0.f, s3 = 0.f;
#pragma unroll 4
    for (int f0 = 0; f0 < HID; f0 += 4) {
        float4 w;
        w.x = W2[(f0 + 0) * OUT_ + o];
        w.y = W2[(f0 + 1) * OUT_ + o];
        w.z = W2[(f0 + 2) * OUT_ + o];
        w.w = W2[(f0 + 3) * OUT_ + o];
        const float4 g0 = *(const float4*)(smem + (grp * JPT + 0) * HID + f0);
        const float4 g1 = *(const float4*)(smem + (grp * JPT + 1) * HID + f0);
        const float4 g2 = *(const float4*)(smem + (grp * JPT + 2) * HID + f0);
        const float4 g3 = *(const float4*)(smem + (grp * JPT + 3) * HID + f0);
        s0 = fmaf(g0.x, w.x, fmaf(g0.y, w.y, fmaf(g0.z, w.z, fmaf(g0.w, w.w, s0))));
        s1 = fmaf(g1.x, w.x, fmaf(g1.y, w.y, fmaf(g1.z, w.z, fmaf(g1.w, w.w, s1))));
        s2 = fmaf(g2.x, w.x, fmaf(g2.y, w.y, fmaf(g2.z, w.z, fmaf(g2.w, w.w, s2))));
        s3 = fmaf(g3.x, w.x, fmaf(g3.y, w.y, fmaf(g3.z, w.z, fmaf(g3.w, w.w, s3))));
    }

    float* outp = out + ((size_t)b * OUT_ + o) * N_ + j0;
    atomicAdd(outp + 0, s0);
    atomicAdd(outp + 1, s1);
    atomicAdd(outp + 2, s2);
    atomicAdd(outp + 3, s3);
}

// ---------------------------------------------------------------------------
extern "C" void kernel_launch(void* const* d_in, const int* in_sizes, int n_in,
                              void* d_out, int out_size, void* d_ws, size_t ws_size,
                              hipStream_t stream)
{
    const float* x  = (const float*)d_in[0];   // (4,32,24,24)
    const float* W1 = (const float*)d_in[1];   // (64,128)
    const float* b1 = (const float*)d_in[2];   // (128,)
    const float* W2 = (const float*)d_in[3];   // (128,32)
    const float* b2 = (const float*)d_in[4];   // (32,)
    float* out = (float*)d_out;                // (4,32,24,24) fp32

    float* px  = (float*)d_ws;                 // B*N*HID
    float* pcb = px + (size_t)B_ * N_ * HID;   // B*N*HID

    proj_kernel<<<B_ * N_, 128, 0, stream>>>(x, W1, b1, b2, px, pcb, out);
    pair_fused<<<dim3(N_ / TJB, ISPLIT, B_), 256, 0, stream>>>(px, pcb, W2, out);
}

// Round 6
// 39.048 us; speedup vs baseline: 1.1229x; 1.1229x over previous
//
#include <hip/hip_runtime.h>

// Problem constants (fixed by reference: B=4, C=32, H=W=24, hid=128, out=32)
#define B_     4
#define C_     32
#define N_     576     // H*W
#define HID    128
#define OUT_   32
#define JPT    4       // j's per THREAD (register-tiled)
#define GRPS   8       // 32-lane groups per block
#define TJB    (JPT * GRPS)     // 32 j's per block
#define ISPLIT 12      // i-range split for occupancy
#define ICH    (N_ / ISPLIT)    // 48 i's per block
#define HALF   24      // px rows register-resident per volley

// ---------------------------------------------------------------------------
// Kernel A: per-token projections.  (unchanged from R4 — control)
//   tokens[b,n,c] = x[(b*C+c)*N + n]
//   px[b,n,f]  = sum_c tok[c] * W1[c,f]
//   pcb[b,n,f] = sum_c tok[c] * W1[C+c,f] + b1[f]
// ---------------------------------------------------------------------------
__global__ __launch_bounds__(128) void proj_kernel(
    const float* __restrict__ x, const float* __restrict__ W1,
    const float* __restrict__ b1,
    float* __restrict__ px, float* __restrict__ pcb)
{
    const int blk = blockIdx.x;       // 0 .. B*N-1
    const int b = blk / N_;
    const int n = blk % N_;
    const int f = threadIdx.x;        // 0..127

    __shared__ float tok[C_];
    if (f < C_) tok[f] = x[(b * C_ + f) * N_ + n];
    __syncthreads();

    float accx = 0.f, accc = 0.f;
#pragma unroll
    for (int c = 0; c < C_; ++c) {
        const float t = tok[c];
        accx = fmaf(t, W1[c * HID + f], accx);
        accc = fmaf(t, W1[(C_ + c) * HID + f], accc);
    }
    const int base = (b * N_ + n) * HID + f;
    px[base]  = accx;
    pcb[base] = accc + b1[f];
}

// ---------------------------------------------------------------------------
// Kernel B: partial pairwise relu-sum, px REGISTER-resident.
//   gpart[b,isp,j,f] = sum_{i in chunk(isp)} relu(px[b,i,f] + pcb[b,j,f])
// Block = 256 threads = 8 groups x 32 lanes; group owns 4 j's, lane owns a
// float4 of features. The thread's 48-row px column is loaded in two
// 24-deep independent register volleys (one latency exposure each), then
// the accumulation loop is PURE VALU — no loads, no LDS, no barriers.
// ---------------------------------------------------------------------------
__global__ __launch_bounds__(256) void pair_regs(
    const float* __restrict__ px, const float* __restrict__ pcb,
    float* __restrict__ gpart)
{
    const int jt   = blockIdx.x;          // 0 .. N/TJB-1  (18)
    const int isp  = blockIdx.y;          // 0 .. ISPLIT-1 (12)
    const int b    = blockIdx.z;          // 0 .. B-1
    const int tid  = threadIdx.x;
    const int lane = tid & 31;            // f-quad index
    const int grp  = tid >> 5;            // 0..7
    const int j0   = jt * TJB + grp * JPT;

    // pcb for this thread's 4 j's — issued first, latency overlaps volleys.
    float4 c[JPT];
#pragma unroll
    for (int jp = 0; jp < JPT; ++jp)
        c[jp] = *(const float4*)(pcb + ((size_t)b * N_ + j0 + jp) * HID + 4 * lane);

    float4 acc[JPT];
#pragma unroll
    for (int jp = 0; jp < JPT; ++jp)
        acc[jp] = make_float4(0.f, 0.f, 0.f, 0.f);

    const float* __restrict__ p = px + ((size_t)b * N_ + isp * ICH) * HID + 4 * lane;

#pragma unroll
    for (int h = 0; h < ICH / HALF; ++h) {
        float4 A[HALF];
#pragma unroll
        for (int i = 0; i < HALF; ++i)
            A[i] = *(const float4*)(p + (size_t)(h * HALF + i) * HID);
#pragma unroll
        for (int i = 0; i < HALF; ++i) {
#pragma unroll
            for (int jp = 0; jp < JPT; ++jp) {
                acc[jp].x += fmaxf(A[i].x + c[jp].x, 0.f);
                acc[jp].y += fmaxf(A[i].y + c[jp].y, 0.f);
                acc[jp].z += fmaxf(A[i].z + c[jp].z, 0.f);
                acc[jp].w += fmaxf(A[i].w + c[jp].w, 0.f);
            }
        }
    }

#pragma unroll
    for (int jp = 0; jp < JPT; ++jp)
        *(float4*)(gpart + (((size_t)b * ISPLIT + isp) * N_ + j0 + jp) * HID + 4 * lane) = acc[jp];
}

// ---------------------------------------------------------------------------
// Kernel C: reduce partials + output GEMM.  (unchanged from R4 — control)
//   g[b,j,f] = sum_isp gpart[b,isp,j,f]
//   out[b,o,j] = sum_f g[b,j,f]*W2[f,o] + N*b2[o]
// ---------------------------------------------------------------------------
__global__ __launch_bounds__(128) void finish_kernel(
    const float* __restrict__ gpart, const float* __restrict__ W2,
    const float* __restrict__ b2, float* __restrict__ out)
{
    const int jt = blockIdx.x;    // 0 .. N/4-1
    const int b  = blockIdx.y;
    const int f  = threadIdx.x;   // 0..127
    const int j0 = jt * 4;

    __shared__ float gl[4][HID];
#pragma unroll
    for (int jj = 0; jj < 4; ++jj) {
        float s = 0.f;
#pragma unroll
        for (int isp = 0; isp < ISPLIT; ++isp)
            s += gpart[(((size_t)b * ISPLIT + isp) * N_ + j0 + jj) * HID + f];
        gl[jj][f] = s;
    }
    __syncthreads();

    const int o  = threadIdx.x & 31;
    const int jj = threadIdx.x >> 5;
    float acc = 0.f;
#pragma unroll
    for (int h = 0; h < HID; ++h)
        acc = fmaf(gl[jj][h], W2[h * OUT_ + o], acc);   // gl: broadcast, W2: coalesced
    acc += (float)N_ * b2[o];

    out[((size_t)b * OUT_ + o) * N_ + j0 + jj] = acc;
}

// ---------------------------------------------------------------------------
extern "C" void kernel_launch(void* const* d_in, const int* in_sizes, int n_in,
                              void* d_out, int out_size, void* d_ws, size_t ws_size,
                              hipStream_t stream)
{
    const float* x  = (const float*)d_in[0];   // (4,32,24,24)
    const float* W1 = (const float*)d_in[1];   // (64,128)
    const float* b1 = (const float*)d_in[2];   // (128,)
    const float* W2 = (const float*)d_in[3];   // (128,32)
    const float* b2 = (const float*)d_in[4];   // (32,)
    float* out = (float*)d_out;                // (4,32,24,24) fp32

    float* px    = (float*)d_ws;                       // B*N*HID
    float* pcb   = px  + (size_t)B_ * N_ * HID;        // B*N*HID
    float* gpart = pcb + (size_t)B_ * N_ * HID;        // B*ISPLIT*N*HID (~14.2 MB)

    proj_kernel<<<B_ * N_, 128, 0, stream>>>(x, W1, b1, px, pcb);
    pair_regs<<<dim3(N_ / TJB, ISPLIT, B_), 256, 0, stream>>>(px, pcb, gpart);
    finish_kernel<<<dim3(N_ / 4, B_), 128, 0, stream>>>(gpart, W2, b2, out);
}